// Round 8
// baseline (195.778 us; speedup 1.0000x reference)
//
#include <hip/hip_runtime.h>
#include <stdint.h>

typedef short s16x8 __attribute__((ext_vector_type(8)));
typedef float f32x4 __attribute__((ext_vector_type(4)));
typedef unsigned long long u64;

#define IN_F   256
#define OUT_F  256
#define BATCH  16384
#define NB     31
#define KONE   8192
#define KTOT   8448

typedef const __attribute__((address_space(1))) void* as1cvp;
typedef __attribute__((address_space(3))) void* as3vp;

__device__ __forceinline__ unsigned short f2bf(float f) {
    unsigned u = __float_as_uint(f);
    u += 0x7FFFu + ((u >> 16) & 1u);   // RNE
    return (unsigned short)(u >> 16);
}

// ---------------- kernel 1: fused prep --------------------------------------
// blk 0..255  : column min/max partials over 64 rows -> pmn/pmx[256][256]
// blk 256..511: Haar-synthesize Wb row o = blk-256 (weights loaded once)
__global__ __launch_bounds__(256) void prep1(
    const float* __restrict__ x, const float* __restrict__ bw,
    const float* __restrict__ sw, const float* __restrict__ sc,
    float* __restrict__ pmn, float* __restrict__ pmx,
    unsigned short* __restrict__ Wb) {
    const int blk = blockIdx.x, t = threadIdx.x;
    if (blk < 256) {
        const int b0 = blk * 64;
        float mn = 3.4e38f, mx = -3.4e38f;
        for (int r = 0; r < 64; ++r) {
            float v = x[(size_t)(b0 + r) * IN_F + t];
            mn = fminf(mn, v);
            mx = fmaxf(mx, v);
        }
        pmn[blk * 256 + t] = mn;
        pmx[blk * 256 + t] = mx;
    } else {
        const int o = blk - 256, i = t;
        const float s = sc[o * IN_F + i];
        const float* swp = sw + (size_t)(o * IN_F + i) * NB;
        float w[NB];
#pragma unroll
        for (int k = 0; k < NB; ++k) w[k] = swp[k];
        unsigned short* dst = Wb + (size_t)o * KTOT + i * 32;
#pragma unroll
        for (int q = 0; q < 4; ++q) {
            union { s16x8 v; unsigned short s8[8]; } pk;
#pragma unroll
            for (int e = 0; e < 8; ++e) {
                int j = q * 8 + e;
                float acc = 0.f;
#pragma unroll
                for (int l = 0; l < 5; ++l) {
                    int kk = (1 << l) - 1 + (j >> (5 - l));
                    acc += (((j >> (4 - l)) & 1) ? -w[kk] : w[kk]);
                }
                pk.s8[e] = f2bf(acc * s);
            }
            *(s16x8*)(dst + q * 8) = pk.v;
        }
        Wb[(size_t)o * KTOT + KONE + i] = f2bf(bw[o * IN_F + i]);
    }
}

// ---------------- kernel 2: fused [redundant reduce] + leaves, NATURAL lt[b][i]
// Verified chain (R5 pass): xn=(x-xmin)*rden, leaf=(int)(xn*32), OOB -> 255.
__global__ __launch_bounds__(256) void leaf2(
    const float* __restrict__ x, const float* __restrict__ pmn,
    const float* __restrict__ pmx, unsigned char* __restrict__ lt) {
    __shared__ float xminsh[IN_F], rdnsh[IN_F];
    const int t = threadIdx.x;
    {
        float mn0 = 3.4e38f, mn1 = 3.4e38f, mx0 = -3.4e38f, mx1 = -3.4e38f;
#pragma unroll 8
        for (int b = 0; b < 256; b += 2) {
            mn0 = fminf(mn0, pmn[(size_t)b * 256 + t]);
            mn1 = fminf(mn1, pmn[(size_t)(b + 1) * 256 + t]);
            mx0 = fmaxf(mx0, pmx[(size_t)b * 256 + t]);
            mx1 = fmaxf(mx1, pmx[(size_t)(b + 1) * 256 + t]);
        }
        float mn = fminf(mn0, mn1), mx = fmaxf(mx0, mx1);
        xminsh[t] = mn;
        rdnsh[t] = 1.0f / (mx - mn + 1e-8f);   // verified chain: rcp-mult
    }
    __syncthreads();
    const int lane = t & 63, w = t >> 6;
    const int b0 = blockIdx.x * 64;
    const float4 mn = *(const float4*)(xminsh + lane * 4);
    const float4 rd = *(const float4*)(rdnsh + lane * 4);
#pragma unroll 4
    for (int r = 0; r < 16; ++r) {
        int row = b0 + w * 16 + r;
        float4 v = *(const float4*)(x + (size_t)row * IN_F + lane * 4);
        unsigned b[4];
        float xs[4] = {v.x, v.y, v.z, v.w};
        float ms[4] = {mn.x, mn.y, mn.z, mn.w};
        float rs[4] = {rd.x, rd.y, rd.z, rd.w};
#pragma unroll
        for (int e = 0; e < 4; ++e) {
            float xn = (xs[e] - ms[e]) * rs[e];
            int l = (int)(xn * 32.0f);
            b[e] = (l >= 0 && l < 32) ? (unsigned)l : 255u;
        }
        unsigned pk = b[0] | (b[1] << 8) | (b[2] << 16) | (b[3] << 24);
        *(unsigned*)(lt + (size_t)row * IN_F + lane * 4) = pk;
    }
}

// ---------------- kernel 3: BARRIER-FREE one-hot GEMM -----------------------
// Wave-independent: each wave owns M64xN32, stages ITS OWN 32 N-rows into a
// PRIVATE 4-deep LDS ring (16KB/wave, 32KB/blk), 2 kb ahead, synced only by
// exact counted s_waitcnt vmcnt. ZERO barriers. A is register-synthesized
// one-hot (verified R2/R3/R5) -> no Ash, no bank conflicts. Window ordering is
// locked by zero-cost compiler fences (asm ""::: "memory"); leaf loads kept
// alive by an END-of-iteration pin, where the preceding vmcnt(8) has already
// drained them (compiler's value-wait is satisfied, costs ~0) -- fixes R7's
// top-of-loop pin that forced a premature drain, while still preventing DCE
// of the uniform-stream clamped loads in a peeled last iteration (rule #17).
__global__ __launch_bounds__(128, 2) void gemm_kan(
    const float* __restrict__ x,
    const unsigned short* __restrict__ Wb,
    const unsigned char* __restrict__ lt,
    float* __restrict__ out)
{
    __shared__ unsigned short Bsh[2][4][2048];   // [wave][ring][4KB] = 32KB

    const int t     = threadIdx.x;     // 0..127
    const int lane  = t & 63;
    const int wv    = t >> 6;          // 0,1
    const int mtile = blockIdx.x;      // 0..255
    const int ntile = blockIdx.y;      // 0..3

    const int rr = lane & 15, kq = lane >> 4;
    const int mbase = mtile * 64;
    const int nb    = ntile * 64 + wv * 32;

    // B glds source: wave stages rows nb+8q+(lane>>3), chunk pre-swizzled by
    // (lane&7)^(lane>>3) -> LDS byte (r<<7)+((c^(r&7))<<4) linear-dest law.
    const unsigned char* bbase = (const unsigned char*)(Wb
        + (size_t)(nb + (lane >> 3)) * KTOT
        + (((lane & 7) ^ (lane >> 3)) << 3));

    const unsigned char* lp0 = lt + (size_t)(mbase +  0 + rr) * IN_F;
    const unsigned char* lp1 = lt + (size_t)(mbase + 16 + rr) * IN_F;
    const unsigned char* lp2 = lt + (size_t)(mbase + 32 + rr) * IN_F;
    const unsigned char* lp3 = lt + (size_t)(mbase + 48 + rr) * IN_F;

    int boff[2][2];   // [ks][nt] byte offsets within one 4KB ring slot
#pragma unroll
    for (int ks = 0; ks < 2; ++ks)
#pragma unroll
        for (int nt = 0; nt < 2; ++nt) {
            int n2 = nt * 16 + rr, c = ks * 4 + kq;
            boff[ks][nt] = (n2 << 7) + ((c ^ (n2 & 7)) << 4);
        }

#define FENCE() asm volatile("" ::: "memory")

#define STAGEW(KB, BUF)                                                        \
    {                                                                          \
        const unsigned char* _s = bbase + (size_t)(KB) * 128;                  \
        unsigned short* _d = &Bsh[wv][BUF][0];                                 \
        _Pragma("unroll")                                                      \
        for (int q = 0; q < 4; ++q)                                            \
            __builtin_amdgcn_global_load_lds(                                  \
                (as1cvp)(_s + (size_t)q * 8 * KTOT * 2),                       \
                (as3vp)(uint32_t)(uintptr_t)(_d + q * 512), 16, 0, 0);         \
    }

#define ASYNTH(LW, JJ, KS, AF)                                                 \
    {                                                                          \
        const int L = (int)(((LW) >> ((((JJ) << 1) | (KS)) << 3)) & 255u);     \
        unsigned hot = ((L >> 3) == kq) ? (0x3F80u << ((L & 1) << 4)) : 0u;    \
        int slot = (L >> 1) & 3;                                               \
        union { s16x8 v; unsigned u[4]; } a;                                   \
        a.u[0] = (slot == 0) ? hot : 0u;                                       \
        a.u[1] = (slot == 1) ? hot : 0u;                                       \
        a.u[2] = (slot == 2) ? hot : 0u;                                       \
        a.u[3] = (slot == 3) ? hot : 0u;                                       \
        AF = a.v;                                                              \
    }

#define MFMASTEP(BUF, JJ)                                                      \
    {                                                                          \
        const char* bb = (const char*)&Bsh[wv][BUF][0];                        \
        _Pragma("unroll")                                                      \
        for (int ks = 0; ks < 2; ++ks) {                                       \
            s16x8 b0 = *(const s16x8*)(bb + boff[ks][0]);                      \
            s16x8 b1 = *(const s16x8*)(bb + boff[ks][1]);                      \
            s16x8 a0, a1, a2, a3;                                              \
            ASYNTH(Lc0, JJ, ks, a0); ASYNTH(Lc1, JJ, ks, a1);                  \
            ASYNTH(Lc2, JJ, ks, a2); ASYNTH(Lc3, JJ, ks, a3);                  \
            __builtin_amdgcn_s_setprio(1);                                     \
            acc[0][0] = __builtin_amdgcn_mfma_f32_16x16x32_bf16(a0, b0, acc[0][0], 0, 0, 0); \
            acc[0][1] = __builtin_amdgcn_mfma_f32_16x16x32_bf16(a0, b1, acc[0][1], 0, 0, 0); \
            acc[1][0] = __builtin_amdgcn_mfma_f32_16x16x32_bf16(a1, b0, acc[1][0], 0, 0, 0); \
            acc[1][1] = __builtin_amdgcn_mfma_f32_16x16x32_bf16(a1, b1, acc[1][1], 0, 0, 0); \
            acc[2][0] = __builtin_amdgcn_mfma_f32_16x16x32_bf16(a2, b0, acc[2][0], 0, 0, 0); \
            acc[2][1] = __builtin_amdgcn_mfma_f32_16x16x32_bf16(a2, b1, acc[2][1], 0, 0, 0); \
            acc[3][0] = __builtin_amdgcn_mfma_f32_16x16x32_bf16(a3, b0, acc[3][0], 0, 0, 0); \
            acc[3][1] = __builtin_amdgcn_mfma_f32_16x16x32_bf16(a3, b1, acc[3][1], 0, 0, 0); \
            __builtin_amdgcn_s_setprio(0);                                     \
        }                                                                      \
    }

    // prologue (fenced windows lock FIFO order): leaves, B(0), B(1) -> 12 in flight
    u64 Lc0 = *(const u64*)lp0, Lc1 = *(const u64*)lp1;
    u64 Lc2 = *(const u64*)lp2, Lc3 = *(const u64*)lp3;
    FENCE();
    STAGEW(0, 0);
    FENCE();
    STAGEW(1, 1);

    f32x4 acc[4][2] = {};

    for (int g = 0; g < 128; g += 4) {
        // leaf u64s for next group; clamped reload on last group keeps the
        // vmcnt stream uniform (kept alive by the end-of-iteration pin)
        const int goff = (g + 4 < 128) ? 2 * (g + 4) : 248;
        u64 Ln0 = *(const u64*)(lp0 + goff);
        u64 Ln1 = *(const u64*)(lp1 + goff);
        u64 Ln2 = *(const u64*)(lp2 + goff);
        u64 Ln3 = *(const u64*)(lp3 + goff);
        FENCE();

        // FIFO (oldest->newest) after issue: [g][g+1][Ln][g+2]
        STAGEW(g + 2, ((g + 2) & 3));
        asm volatile("s_waitcnt vmcnt(12)" ::: "memory");   // g landed
        MFMASTEP((g & 3), 0);

        STAGEW(g + 3, ((g + 3) & 3));
        asm volatile("s_waitcnt vmcnt(12)" ::: "memory");   // g+1 landed
        MFMASTEP(((g + 1) & 3), 1);

        STAGEW(g + 4, ((g + 4) & 3));
        asm volatile("s_waitcnt vmcnt(8)" ::: "memory");    // Ln + g+2 landed
        MFMASTEP(((g + 2) & 3), 2);

        STAGEW(g + 5, ((g + 5) & 3));
        asm volatile("s_waitcnt vmcnt(8)" ::: "memory");    // g+3 landed
        MFMASTEP(((g + 3) & 3), 3);

        // keep-alive pin: Ln already drained by vmcnt(8) above -> wait is
        // satisfied (zero cost), but prevents DCE of last-group loads
        asm volatile("" : "+v"(Ln0), "+v"(Ln1), "+v"(Ln2), "+v"(Ln3));
        Lc0 = Ln0; Lc1 = Ln1; Lc2 = Ln2; Lc3 = Ln3;
    }

    // dense relu(x) tail kb 128..131: ring holds 128,129; stage 130,131
    // (wave-private slots 2,3; last read completed >=2 groups ago)
    STAGEW(130, 2);
    STAGEW(131, 3);
    asm volatile("s_waitcnt vmcnt(0)" ::: "memory");
#pragma unroll
    for (int kb = 128; kb < 132; ++kb) {
        const char* bb = (const char*)&Bsh[wv][kb & 3][0];
#pragma unroll
        for (int ks = 0; ks < 2; ++ks) {
            s16x8 b0 = *(const s16x8*)(bb + boff[ks][0]);
            s16x8 b1 = *(const s16x8*)(bb + boff[ks][1]);
            s16x8 af[4];
#pragma unroll
            for (int mt = 0; mt < 4; ++mt) {
                const float* xr = x + (size_t)(mbase + mt * 16 + rr) * IN_F
                                    + (kb - 128) * 64 + ks * 32 + kq * 8;
                union { s16x8 v; unsigned short s8[8]; } a;
#pragma unroll
                for (int e = 0; e < 8; ++e) a.s8[e] = f2bf(fmaxf(xr[e], 0.0f));
                af[mt] = a.v;
            }
            __builtin_amdgcn_s_setprio(1);
#pragma unroll
            for (int mt = 0; mt < 4; ++mt) {
                acc[mt][0] = __builtin_amdgcn_mfma_f32_16x16x32_bf16(af[mt], b0, acc[mt][0], 0, 0, 0);
                acc[mt][1] = __builtin_amdgcn_mfma_f32_16x16x32_bf16(af[mt], b1, acc[mt][1], 0, 0, 0);
            }
            __builtin_amdgcn_s_setprio(0);
        }
    }

    // epilogue: C/D layout col=lane&15, row=(lane>>4)*4+reg (m89/m91)
    const int rq = lane >> 4;
#pragma unroll
    for (int mt = 0; mt < 4; ++mt)
#pragma unroll
        for (int nt = 0; nt < 2; ++nt)
#pragma unroll
            for (int v = 0; v < 4; ++v) {
                int row = mbase + mt * 16 + rq * 4 + v;
                int col = nb + nt * 16 + rr;
                out[(size_t)row * OUT_F + col] = acc[mt][nt][v];
            }
#undef STAGEW
#undef ASYNTH
#undef MFMASTEP
#undef FENCE
}

// ---------------- host ----------------
extern "C" void kernel_launch(void* const* d_in, const int* in_sizes, int n_in,
                              void* d_out, int out_size, void* d_ws, size_t ws_size,
                              hipStream_t stream) {
    (void)in_sizes; (void)n_in; (void)out_size; (void)ws_size;
    const float* x  = (const float*)d_in[0];   // [16384,256]
    const float* bw = (const float*)d_in[1];   // [256,256]
    const float* sw = (const float*)d_in[2];   // [256,256,31]
    const float* sc = (const float*)d_in[3];   // [256,256]
    float* out = (float*)d_out;

    char* ws = (char*)d_ws;
    unsigned short* Wb = (unsigned short*)ws;               // 4,325,376 B
    unsigned char*  lt = (unsigned char*)(ws + 4325376);    // 4,194,304 B  [b][i]
    float* pmn = (float*)(ws + 8519680);                    // 262,144 B
    float* pmx = (float*)(ws + 8781824);                    // 262,144 B

    prep1<<<512, 256, 0, stream>>>(x, bw, sw, sc, pmn, pmx, Wb);
    leaf2<<<256, 256, 0, stream>>>(x, pmn, pmx, lt);
    gemm_kan<<<dim3(256, 4), 128, 0, stream>>>(x, Wb, lt, out);
}

// Round 9
// 162.443 us; speedup vs baseline: 1.2052x; 1.2052x over previous
//
#include <hip/hip_runtime.h>
#include <stdint.h>

typedef short s16x8 __attribute__((ext_vector_type(8)));
typedef float f32x4 __attribute__((ext_vector_type(4)));

#define IN_F   256
#define OUT_F  256
#define BATCH  16384
#define NB     31
#define KONE   8192
#define KTOT   8448

typedef const __attribute__((address_space(1))) void* as1cvp;
typedef __attribute__((address_space(3))) void* as3vp;

__device__ __forceinline__ unsigned short f2bf(float f) {
    unsigned u = __float_as_uint(f);
    u += 0x7FFFu + ((u >> 16) & 1u);   // RNE
    return (unsigned short)(u >> 16);
}

// ---------------- kernel 1: fused prep (verbatim R6, measured-good) ---------
__global__ __launch_bounds__(256) void prep1(
    const float* __restrict__ x, const float* __restrict__ bw,
    const float* __restrict__ sw, const float* __restrict__ sc,
    float* __restrict__ pmn, float* __restrict__ pmx,
    unsigned short* __restrict__ Wb) {
    const int blk = blockIdx.x, t = threadIdx.x;
    if (blk < 256) {
        const int b0 = blk * 64;
        float mn = 3.4e38f, mx = -3.4e38f;
        for (int r = 0; r < 64; ++r) {
            float v = x[(size_t)(b0 + r) * IN_F + t];
            mn = fminf(mn, v);
            mx = fmaxf(mx, v);
        }
        pmn[blk * 256 + t] = mn;
        pmx[blk * 256 + t] = mx;
    } else {
        const int o = blk - 256, i = t;
        const float s = sc[o * IN_F + i];
        const float* swp = sw + (size_t)(o * IN_F + i) * NB;
        float w[NB];
#pragma unroll
        for (int k = 0; k < NB; ++k) w[k] = swp[k];
        unsigned short* dst = Wb + (size_t)o * KTOT + i * 32;
#pragma unroll
        for (int q = 0; q < 4; ++q) {
            union { s16x8 v; unsigned short s8[8]; } pk;
#pragma unroll
            for (int e = 0; e < 8; ++e) {
                int j = q * 8 + e;
                float acc = 0.f;
#pragma unroll
                for (int l = 0; l < 5; ++l) {
                    int kk = (1 << l) - 1 + (j >> (5 - l));
                    acc += (((j >> (4 - l)) & 1) ? -w[kk] : w[kk]);
                }
                pk.s8[e] = f2bf(acc * s);
            }
            *(s16x8*)(dst + q * 8) = pk.v;
        }
        Wb[(size_t)o * KTOT + KONE + i] = f2bf(bw[o * IN_F + i]);
    }
}

// ---------------- kernel 2: reduce + transposed leaves (verbatim R6) --------
__global__ __launch_bounds__(256) void leaf2t(
    const float* __restrict__ x, const float* __restrict__ pmn,
    const float* __restrict__ pmx, unsigned char* __restrict__ lt) {
    __shared__ unsigned char lsh[256 * 68];    // [i][r], stride 68 (odd dword)
    __shared__ float xminsh[IN_F], rdnsh[IN_F];
    const int t = threadIdx.x;
    {
        float mn0 = 3.4e38f, mn1 = 3.4e38f, mx0 = -3.4e38f, mx1 = -3.4e38f;
#pragma unroll 8
        for (int b = 0; b < 256; b += 2) {
            mn0 = fminf(mn0, pmn[(size_t)b * 256 + t]);
            mn1 = fminf(mn1, pmn[(size_t)(b + 1) * 256 + t]);
            mx0 = fmaxf(mx0, pmx[(size_t)b * 256 + t]);
            mx1 = fmaxf(mx1, pmx[(size_t)(b + 1) * 256 + t]);
        }
        float mn = fminf(mn0, mn1), mx = fmaxf(mx0, mx1);
        xminsh[t] = mn;
        rdnsh[t] = 1.0f / (mx - mn + 1e-8f);   // verified chain: rcp-mult
    }
    __syncthreads();
    const float xmn = xminsh[t], rdn = rdnsh[t];
    const int b0 = blockIdx.x * 64;
    for (int r = 0; r < 64; ++r) {
        float v = x[(size_t)(b0 + r) * IN_F + t];
        float xn = (v - xmn) * rdn;
        int l = (int)(xn * 32.0f);
        lsh[t * 68 + r] = (l >= 0 && l < 32) ? (unsigned char)l : (unsigned char)255;
    }
    __syncthreads();
    const int lane = t & 63, w = t >> 6;
    const unsigned* lshU = (const unsigned*)lsh;
#pragma unroll
    for (int ib = 0; ib < 16; ++ib) {
        int i = ib * 16 + w * 4 + (lane >> 4);
        unsigned val = lshU[i * 17 + (lane & 15)];
        *(unsigned*)(lt + (size_t)i * BATCH + b0 + (lane & 15) * 4) = val;
    }
}

// ---------------- kernel 3: R6 winner + T3/T4 counted-vmcnt raw barrier -----
// R6 (87.2us, best of session) minus its structural stall: __syncthreads forced
// s_waitcnt vmcnt(0) each kb, draining in-flight glds (guide m97 ~20% stall).
// Here: B in a 4-deep SHARED ring staged 2 kb ahead; per kb exactly ONE raw
// s_barrier + counted vmcnt(5). FIFO at loop top = [S(kb):4, L(kb):1,
// S(kb+1):4, L(kb+1):1] -> vmcnt(5) drains exactly S(kb)+L(kb) (own half);
// barrier then proves the other wave did the same for ITS half. Ring WAR is
// safe at depth 4: slot (kb+2)&3's last reader (MFMA(kb-2), both waves)
// completed before barrier(kb-1), which precedes this stage issue. A one-hot
// stays in LDS (O(1) VALU/kb -- reg-A costs ~140 VALU/kb, R8's regression).
// A rows are wave-private (R6-verified) so A needs no barrier. All math,
// swizzles, fragment layouts, K-order bit-identical to R6.
__global__ __launch_bounds__(128, 2) void gemm_kan(
    const float* __restrict__ x,
    const unsigned short* __restrict__ Wb,
    const unsigned char* __restrict__ lt,
    float* __restrict__ out)
{
    __shared__ unsigned short Ash[64 * 64];        // 8KB, XOR-swizzled chunks
    __shared__ unsigned short Bsh[4 * 64 * 64];    // 32KB, 4-deep ring

    const int t     = threadIdx.x;     // 0..127
    const int lane  = t & 63;
    const int wv    = t >> 6;          // 0,1
    const int mtile = blockIdx.x;
    const int ntile = blockIdx.y;

    // zero A tile: each wave zeroes ITS OWN 32 rows (wave-private invariant)
    {
        uint4 z; z.x = z.y = z.z = z.w = 0u;
        uint4* a4 = (uint4*)(Ash + wv * 2048);
#pragma unroll
        for (int r = 0; r < 4; ++r) a4[lane + r * 64] = z;
    }

    // B glds source base (pre-swizzled: n&7 == lane>>3, q-independent);
    // wave wv stages N-rows 32wv..+31 into ring slot + wv*2048
    const unsigned char* bbase = (const unsigned char*)(Wb
        + (size_t)(ntile * 64 + wv * 32 + (lane >> 3)) * KTOT
        + (((lane & 7) ^ (lane >> 3)) << 3));

    const int am = t >> 1;             // 0..63; wave0 -> 0..31, wave1 -> 32..63
    const int ag = t & 1;
    const size_t lrow0 = (size_t)mtile * 64;
    int ps = -1;

    const int rr = lane & 15, kq = lane >> 4;
    f32x4 acc[2][4] = {};

#define STAGE(KB, SLOT)                                                        \
    {                                                                          \
        const unsigned char* _s = bbase + (size_t)(KB) * 128;                  \
        unsigned short* _d = Bsh + (SLOT) * 4096 + wv * 2048;                  \
        _Pragma("unroll")                                                      \
        for (int q = 0; q < 4; ++q)                                            \
            __builtin_amdgcn_global_load_lds(                                  \
                (as1cvp)(_s + (size_t)q * 8 * KTOT * 2),                       \
                (as3vp)(uint32_t)(uintptr_t)(_d + q * 512), 16, 0, 0);         \
    }

#define AONEHOT(LF)                                                            \
    {                                                                          \
        if (ps >= 0) Ash[ps] = 0;                                              \
        int l = (LF);                                                          \
        if (l < 32) {                                                          \
            int c = (ag << 2) + (l >> 3);                                      \
            ps = (am << 6) + ((c ^ (am & 7)) << 3) + (l & 7);                  \
            Ash[ps] = 0x3F80;                                                  \
        } else ps = -1;                                                        \
    }

#define BARRIER()                                                              \
    asm volatile("" ::: "memory");                                             \
    __builtin_amdgcn_s_barrier();                                              \
    asm volatile("" ::: "memory")

#define MFMAPH(KB)                                                             \
    {                                                                          \
        const unsigned short* bb = Bsh + ((KB) & 3) * 4096;                    \
        __builtin_amdgcn_s_setprio(1);                                         \
        _Pragma("unroll")                                                      \
        for (int ks = 0; ks < 2; ++ks) {                                       \
            const int c = (ks << 2) + kq;                                      \
            s16x8 af[2], bfr[4];                                               \
            _Pragma("unroll")                                                  \
            for (int mt = 0; mt < 2; ++mt) {                                   \
                int m = wv * 32 + mt * 16 + rr;                                \
                af[mt] = *(const s16x8*)&Ash[(m << 6) + ((c ^ (m & 7)) << 3)]; \
            }                                                                  \
            _Pragma("unroll")                                                  \
            for (int nt = 0; nt < 4; ++nt) {                                   \
                int n = nt * 16 + rr;                                          \
                bfr[nt] = *(const s16x8*)&bb[(n << 6) + ((c ^ (n & 7)) << 3)]; \
            }                                                                  \
            _Pragma("unroll")                                                  \
            for (int mt = 0; mt < 2; ++mt)                                     \
                _Pragma("unroll")                                              \
                for (int nt = 0; nt < 4; ++nt)                                 \
                    acc[mt][nt] = __builtin_amdgcn_mfma_f32_16x16x32_bf16(     \
                        af[mt], bfr[nt], acc[mt][nt], 0, 0, 0);                \
        }                                                                      \
        __builtin_amdgcn_s_setprio(0);                                         \
    }

    // prologue: FIFO = [S0:4, L0:1, S1:4, L1:1] = 10 outstanding
    STAGE(0, 0);
    unsigned char lf0 = lt[(size_t)(0 + ag) * BATCH + lrow0 + am];
    STAGE(1, 1);
    unsigned char lf1 = lt[(size_t)(2 + ag) * BATCH + lrow0 + am];

    // main loop: kb = 0..125, unrolled x2 (named lf0/lf1; rule #20)
    for (int kb = 0; kb < 126; kb += 2) {
        // ---- even body (kb) ----
        asm volatile("s_waitcnt vmcnt(5)" ::: "memory");  // S(kb)+L(kb) landed
        AONEHOT(lf0);
        STAGE(kb + 2, (kb + 2) & 3);
        lf0 = lt[(size_t)((kb + 2) * 2 + ag) * BATCH + lrow0 + am];
        BARRIER();                                        // everyone's S(kb) in LDS
        MFMAPH(kb);
        // ---- odd body (kb+1) ----
        asm volatile("s_waitcnt vmcnt(5)" ::: "memory");
        AONEHOT(lf1);
        STAGE(kb + 3, (kb + 3) & 3);
        lf1 = lt[(size_t)((kb + 3) * 2 + ag) * BATCH + lrow0 + am];
        BARRIER();
        MFMAPH(kb + 1);
    }

    // tail: kb=126 (one-hot, lf0 from kb=124), kb=127 (lf1 from 125)
    asm volatile("s_waitcnt vmcnt(5)" ::: "memory");      // drains S126+L126
    AONEHOT(lf0);
    STAGE(128, 0);
    BARRIER();
    MFMAPH(126);

    asm volatile("s_waitcnt vmcnt(4)" ::: "memory");      // drains S127+L127
    AONEHOT(lf1);
    STAGE(129, 1);
    BARRIER();
    MFMAPH(127);

    // dense relu(x) tail kb 128..131 (wave-private 32-row overwrite)
#pragma unroll
    for (int kb = 128; kb < 132; ++kb) {
        if (kb < 131) { asm volatile("s_waitcnt vmcnt(4)" ::: "memory"); }
        else          { asm volatile("s_waitcnt vmcnt(0)" ::: "memory"); }
        {
            const float* xr = x + (size_t)(mtile * 64 + wv * 32) * IN_F + (kb - 128) * 64 + lane;
            const int cslot = (lane >> 3);
#pragma unroll
            for (int m0 = 0; m0 < 32; ++m0) {
                int m = wv * 32 + m0;
                float v = xr[(size_t)m0 * IN_F];
                Ash[(m << 6) + ((cslot ^ (m & 7)) << 3) + (lane & 7)] = f2bf(fmaxf(v, 0.0f));
            }
        }
        if (kb + 2 < 132) STAGE(kb + 2, (kb + 2) & 3);
        BARRIER();
        MFMAPH(kb);
    }

    // epilogue: C/D layout col=lane&15, row=(lane>>4)*4+reg (m89/m91)
    const int rq = lane >> 4;
#pragma unroll
    for (int mt = 0; mt < 2; ++mt)
#pragma unroll
        for (int nt = 0; nt < 4; ++nt)
#pragma unroll
            for (int v = 0; v < 4; ++v) {
                int row = mtile * 64 + wv * 32 + mt * 16 + rq * 4 + v;
                int col = ntile * 64 + nt * 16 + rr;
                out[(size_t)row * OUT_F + col] = acc[mt][nt][v];
            }
#undef STAGE
#undef AONEHOT
#undef BARRIER
#undef MFMAPH
}

// ---------------- host ----------------
extern "C" void kernel_launch(void* const* d_in, const int* in_sizes, int n_in,
                              void* d_out, int out_size, void* d_ws, size_t ws_size,
                              hipStream_t stream) {
    (void)in_sizes; (void)n_in; (void)out_size; (void)ws_size;
    const float* x  = (const float*)d_in[0];   // [16384,256]
    const float* bw = (const float*)d_in[1];   // [256,256]
    const float* sw = (const float*)d_in[2];   // [256,256,31]
    const float* sc = (const float*)d_in[3];   // [256,256]
    float* out = (float*)d_out;

    char* ws = (char*)d_ws;
    unsigned short* Wb = (unsigned short*)ws;               // 4,325,376 B
    unsigned char*  lt = (unsigned char*)(ws + 4325376);    // 4,194,304 B  [i][b]
    float* pmn = (float*)(ws + 8519680);                    // 262,144 B
    float* pmx = (float*)(ws + 8781824);                    // 262,144 B

    prep1<<<512, 256, 0, stream>>>(x, bw, sw, sc, pmn, pmx, Wb);
    leaf2t<<<256, 256, 0, stream>>>(x, pmn, pmx, lt);
    gemm_kan<<<dim3(256, 4), 128, 0, stream>>>(x, Wb, lt, out);
}